// Round 1
// baseline (154.105 us; speedup 1.0000x reference)
//
#include <hip/hip_runtime.h>
#include <hip/hip_bf16.h>

#define NH   16
#define HD   64
#define SEQ  2048
#define DM   1024
#define QB   64      // q rows per block (4 waves x 16)
#define KVB  32      // keys per LDS tile
#define KSTR 72      // K tile row stride (bf16 elems), 64+8 pad
#define VSTR 40      // V^T tile row stride, 32+8 pad
#define PSTR 40      // P tile row stride, 32+8 pad

typedef __bf16 bf16x8 __attribute__((ext_vector_type(8)));
typedef float  f32x4  __attribute__((ext_vector_type(4)));

__global__ __launch_bounds__(256) void psa_kernel(
    const float* __restrict__ Vg, const float* __restrict__ Kg,
    const float* __restrict__ Qg, float* __restrict__ Og)
{
    __shared__ __bf16 Kt[KVB][KSTR];     // [key][d]
    __shared__ __bf16 Vt[HD][VSTR];      // transposed: [d][key]
    __shared__ __bf16 Pt[4][16][PSTR];   // per-wave silu(S) tile [q][k]

    const int bid  = blockIdx.x;
    const int bh   = bid >> 5;           // 32 q-blocks contiguous per (b,h) for L2 locality
    const int qb   = bid & 31;
    const int b    = bh >> 4;
    const int h    = bh & (NH - 1);
    const int tid  = threadIdx.x;
    const int w    = tid >> 6;
    const int l    = tid & 63;
    const int qr   = l & 15;             // row/col-within-16
    const int kseg = l >> 4;             // 0..3 (k-chunk of 8)
    const int q0   = qb * QB + w * 16;

    const size_t base = (size_t)b * SEQ * DM + (size_t)h * HD;

    // ---- Q fragments (A-layout: lane holds row qr, k = kseg*8..+7), kept all kernel
    bf16x8 qf[2];
#pragma unroll
    for (int ds = 0; ds < 2; ++ds) {
        const float* p = Qg + base + (size_t)(q0 + qr) * DM + ds * 32 + kseg * 8;
        float4 a = *(const float4*)p;
        float4 c = *(const float4*)(p + 4);
        qf[ds][0] = (__bf16)a.x; qf[ds][1] = (__bf16)a.y;
        qf[ds][2] = (__bf16)a.z; qf[ds][3] = (__bf16)a.w;
        qf[ds][4] = (__bf16)c.x; qf[ds][5] = (__bf16)c.y;
        qf[ds][6] = (__bf16)c.z; qf[ds][7] = (__bf16)c.w;
    }

    f32x4 acc[4];
#pragma unroll
    for (int i = 0; i < 4; ++i)
#pragma unroll
        for (int j = 0; j < 4; ++j) acc[i][j] = 0.f;

    const int lrow = tid >> 3;           // 0..31 : key row staged by this thread
    const int ld0  = (tid & 7) * 8;      // 8 d-elements per thread

    for (int kv = 0; kv < SEQ; kv += KVB) {
        __syncthreads();                 // previous tile's LDS reads done
        {
            const float* kp = Kg + base + (size_t)(kv + lrow) * DM + ld0;
            float4 a = *(const float4*)kp;
            float4 c = *(const float4*)(kp + 4);
            __bf16* d = &Kt[lrow][ld0];
            d[0] = (__bf16)a.x; d[1] = (__bf16)a.y; d[2] = (__bf16)a.z; d[3] = (__bf16)a.w;
            d[4] = (__bf16)c.x; d[5] = (__bf16)c.y; d[6] = (__bf16)c.z; d[7] = (__bf16)c.w;

            const float* vp = Vg + base + (size_t)(kv + lrow) * DM + ld0;
            float4 va = *(const float4*)vp;
            float4 vc = *(const float4*)(vp + 4);
            Vt[ld0 + 0][lrow] = (__bf16)va.x; Vt[ld0 + 1][lrow] = (__bf16)va.y;
            Vt[ld0 + 2][lrow] = (__bf16)va.z; Vt[ld0 + 3][lrow] = (__bf16)va.w;
            Vt[ld0 + 4][lrow] = (__bf16)vc.x; Vt[ld0 + 5][lrow] = (__bf16)vc.y;
            Vt[ld0 + 6][lrow] = (__bf16)vc.z; Vt[ld0 + 7][lrow] = (__bf16)vc.w;
        }
        __syncthreads();                 // tiles staged

        // ---- S = Q K^T for two 16-key subtiles, silu, park bf16 P in LDS
#pragma unroll
        for (int kt = 0; kt < 2; ++kt) {
            f32x4 s;
#pragma unroll
            for (int r = 0; r < 4; ++r) s[r] = 0.f;
            bf16x8 kf0 = *(const bf16x8*)&Kt[kt * 16 + qr][kseg * 8];       // d-slice 0
            bf16x8 kf1 = *(const bf16x8*)&Kt[kt * 16 + qr][32 + kseg * 8];  // d-slice 1
            s = __builtin_amdgcn_mfma_f32_16x16x32_bf16(qf[0], kf0, s, 0, 0, 0);
            s = __builtin_amdgcn_mfma_f32_16x16x32_bf16(qf[1], kf1, s, 0, 0, 0);
#pragma unroll
            for (int r = 0; r < 4; ++r) {
                float x = s[r];
                float y = x / (1.f + __expf(-x));   // silu
                Pt[w][kseg * 4 + r][kt * 16 + qr] = (__bf16)y;  // D-layout scatter
            }
        }
        __syncthreads();                 // P visible (cross-lane within wave)

        // ---- out += P * V  (A-layout read of P, B-layout read of V^T)
        bf16x8 pa = *(const bf16x8*)&Pt[w][qr][kseg * 8];
#pragma unroll
        for (int dt = 0; dt < 4; ++dt) {
            bf16x8 vf = *(const bf16x8*)&Vt[dt * 16 + qr][kseg * 8];
            acc[dt] = __builtin_amdgcn_mfma_f32_16x16x32_bf16(pa, vf, acc[dt], 0, 0, 0);
        }
    }

    // ---- epilogue: C/D layout -> global (row = kseg*4+r, col = dt*16+qr)
    float* op = Og + base + (size_t)q0 * DM;
#pragma unroll
    for (int dt = 0; dt < 4; ++dt)
#pragma unroll
        for (int r = 0; r < 4; ++r)
            op[(size_t)(kseg * 4 + r) * DM + dt * 16 + qr] = acc[dt][r];
}

extern "C" void kernel_launch(void* const* d_in, const int* in_sizes, int n_in,
                              void* d_out, int out_size, void* d_ws, size_t ws_size,
                              hipStream_t stream) {
    const float* v = (const float*)d_in[0];
    const float* k = (const float*)d_in[1];
    const float* q = (const float*)d_in[2];
    float* out = (float*)d_out;
    (void)in_sizes; (void)n_in; (void)out_size; (void)d_ws; (void)ws_size;

    dim3 grid(32 * (SEQ / QB));   // 32 (b,h) pairs x 32 q-tiles = 1024 blocks
    dim3 block(256);
    psa_kernel<<<grid, block, 0, stream>>>(v, k, q, out);
}

// Round 2
// 117.058 us; speedup vs baseline: 1.3165x; 1.3165x over previous
//
#include <hip/hip_runtime.h>
#include <hip/hip_bf16.h>

#define SEQ 2048
#define DM  1024
#define NH  16
#define HD  64
#define BH  32            // B*NH
#define QB  128           // q rows per block (4 waves x 32)
#define KVB 64            // keys per tile
#define NT  (SEQ/KVB)     // 32 kv tiles
#define TILE_E (KVB*HD)   // 4096 bf16 per K/V tile

// ws layout (bf16 elements)
#define KWS_OFF 0u        // [BH][NT][64 key][64 d]  swizzled rows
#define VWS_OFF 4194304u  // [BH][NT][64 d][64 kv]   swizzled rows (V transposed)
#define QWS_OFF 8388608u  // [BH][SEQ][64]           plain

typedef __bf16 bf16x8 __attribute__((ext_vector_type(8)));
typedef __bf16 bf16x4 __attribute__((ext_vector_type(4)));
typedef float  f32x4  __attribute__((ext_vector_type(4)));

// swizzled element offset within a 64x64 bf16 tile (row stride 128B):
// byte ^= (row&7)<<4  ==  elem col ^= (row&7)<<3
__device__ __forceinline__ int sw64(int row, int c) {
    return row * 64 + (c ^ ((row & 7) << 3));
}

// ---------------- pre-pass: fp32 -> bf16, head-split, V transposed, swizzle baked ----
__global__ __launch_bounds__(256) void psa_prep(
    const float* __restrict__ V, const float* __restrict__ K,
    const float* __restrict__ Q, __bf16* __restrict__ ws)
{
    const int blk   = blockIdx.x;
    const int which = blk >> 11;                 // 0:Q 1:K 2:V
    const int idx   = (blk & 2047) * 256 + threadIdx.x;  // 16B-chunk id, 0..524287

    if (which == 0) {
        // Qws chunk (bh, s, c8): contents Q[b][s][h*64 + c8*8 .. +7]
        const int c8 = idx & 7, s = (idx >> 3) & 2047, bh = idx >> 14;
        const int b = bh >> 4, h = bh & 15;
        const float* src = Q + ((size_t)(b * SEQ + s)) * DM + h * HD + c8 * 8;
        float4 a = *(const float4*)src, c = *(const float4*)(src + 4);
        bf16x8 o;
        o[0] = (__bf16)a.x; o[1] = (__bf16)a.y; o[2] = (__bf16)a.z; o[3] = (__bf16)a.w;
        o[4] = (__bf16)c.x; o[5] = (__bf16)c.y; o[6] = (__bf16)c.z; o[7] = (__bf16)c.w;
        *(bf16x8*)(ws + QWS_OFF + (size_t)idx * 8) = o;
    } else if (which == 1) {
        // Kws chunk (bh, t, key, cb): contents K[b][t*64+key][h*64 + d0 .. +7], d0=((cb^ (key&7))<<3)
        const int cb = idx & 7, key = (idx >> 3) & 63, t = (idx >> 9) & 31, bh = idx >> 14;
        const int b = bh >> 4, h = bh & 15;
        const int d0 = ((cb ^ (key & 7)) << 3);
        const float* src = K + ((size_t)(b * SEQ + t * 64 + key)) * DM + h * HD + d0;
        float4 a = *(const float4*)src, c = *(const float4*)(src + 4);
        bf16x8 o;
        o[0] = (__bf16)a.x; o[1] = (__bf16)a.y; o[2] = (__bf16)a.z; o[3] = (__bf16)a.w;
        o[4] = (__bf16)c.x; o[5] = (__bf16)c.y; o[6] = (__bf16)c.z; o[7] = (__bf16)c.w;
        *(bf16x8*)(ws + KWS_OFF + (size_t)idx * 8) = o;
    } else {
        // Vws chunk (bh, t, d, cb): contents V[b][t*64 + ks0+j][h*64+d], ks0=((cb^(d&7))<<3)
        const int cb = idx & 7, d = (idx >> 3) & 63, t = (idx >> 9) & 31, bh = idx >> 14;
        const int b = bh >> 4, h = bh & 15;
        const int ks0 = ((cb ^ (d & 7)) << 3);
        const float* src = V + ((size_t)(b * SEQ + t * 64 + ks0)) * DM + h * HD + d;
        bf16x8 o;
#pragma unroll
        for (int j = 0; j < 8; ++j) o[j] = (__bf16)src[(size_t)j * DM];
        *(bf16x8*)(ws + VWS_OFF + (size_t)idx * 8) = o;
    }
}

// ---------------- main kernel ----------------
__global__ __launch_bounds__(256) void psa_main(
    const __bf16* __restrict__ ws, float* __restrict__ Og)
{
    __shared__ __bf16 KT[2][TILE_E];
    __shared__ __bf16 VT[2][TILE_E];
    __shared__ __bf16 PT[4][QB / 4 * KVB];   // per-wave [32 q][64 k] swizzled

    const int bid = blockIdx.x;
    const int swz = (bid & 7) * 64 + (bid >> 3);   // XCD-aware, 512 % 8 == 0
    const int bh  = swz >> 4;
    const int qb  = swz & 15;
    const int b   = bh >> 4, h = bh & 15;
    const int tid = threadIdx.x;
    const int w   = tid >> 6;
    const int l   = tid & 63;
    const int c16 = l & 15;
    const int seg = l >> 4;
    const int q0  = qb * QB + w * 32;

    const __bf16* Kws = ws + KWS_OFF;
    const __bf16* Vws = ws + VWS_OFF;
    const __bf16* Qws = ws + QWS_OFF;

    // Q fragments (B-layout: lane holds col q = c16(+16*qi), k = d = seg*8+j (+32*ds))
    bf16x8 qf[2][2];
#pragma unroll
    for (int qi = 0; qi < 2; ++qi)
#pragma unroll
        for (int ds = 0; ds < 2; ++ds)
            qf[qi][ds] = *(const bf16x8*)(Qws + ((size_t)bh * SEQ + q0 + qi * 16 + c16) * HD + ds * 32 + seg * 8);

    f32x4 acc[2][4];
#pragma unroll
    for (int qi = 0; qi < 2; ++qi)
#pragma unroll
        for (int dt = 0; dt < 4; ++dt)
#pragma unroll
            for (int r = 0; r < 4; ++r) acc[qi][dt][r] = 0.f;

    auto stage = [&](int bf, int t) {
        const size_t tb = ((size_t)bh * NT + t) * TILE_E;
#pragma unroll
        for (int i = 0; i < 2; ++i) {
            const int ch  = w * 2 + i;              // 8 chunks of 1KB per tensor
            const int off = ch * 512 + l * 8;       // elems; lane*16B
            __builtin_amdgcn_global_load_lds(
                (const __attribute__((address_space(1))) void*)(Kws + tb + off),
                (__attribute__((address_space(3))) void*)&KT[bf][ch * 512], 16, 0, 0);
            __builtin_amdgcn_global_load_lds(
                (const __attribute__((address_space(1))) void*)(Vws + tb + off),
                (__attribute__((address_space(3))) void*)&VT[bf][ch * 512], 16, 0, 0);
        }
    };

    stage(0, 0);
    __syncthreads();

    for (int t = 0; t < NT; ++t) {
        const int cur = t & 1;
        if (t + 1 < NT) stage(cur ^ 1, t + 1);   // prefetch next tile (stays in flight)

        // ---- QK^T (swapped: A=K, B=Q) -> silu -> P tile in LDS (b64 writes)
#pragma unroll
        for (int kt = 0; kt < 4; ++kt) {
            bf16x8 kf0 = *(const bf16x8*)&KT[cur][sw64(kt * 16 + c16, seg * 8)];
            bf16x8 kf1 = *(const bf16x8*)&KT[cur][sw64(kt * 16 + c16, 32 + seg * 8)];
#pragma unroll
            for (int qi = 0; qi < 2; ++qi) {
                f32x4 s;
#pragma unroll
                for (int r = 0; r < 4; ++r) s[r] = 0.f;
                s = __builtin_amdgcn_mfma_f32_16x16x32_bf16(kf0, qf[qi][0], s, 0, 0, 0);
                s = __builtin_amdgcn_mfma_f32_16x16x32_bf16(kf1, qf[qi][1], s, 0, 0, 0);
                bf16x4 pw;
#pragma unroll
                for (int r = 0; r < 4; ++r) {
                    float x = s[r];
                    pw[r] = (__bf16)(x / (1.f + __expf(-x)));
                }
                const int prow = qi * 16 + c16;
                const int pc   = kt * 16 + seg * 4;   // 4 consecutive keys per lane
                *(bf16x4*)&PT[w][sw64(prow, pc)] = pw;
            }
        }

        // ---- out += P * V   (A=P from LDS, B=V^T from LDS; all b128 conflict-free)
#pragma unroll
        for (int kc = 0; kc < 2; ++kc) {
            bf16x8 vf[4];
#pragma unroll
            for (int dt = 0; dt < 4; ++dt)
                vf[dt] = *(const bf16x8*)&VT[cur][sw64(dt * 16 + c16, kc * 32 + seg * 8)];
#pragma unroll
            for (int qi = 0; qi < 2; ++qi) {
                const int prow = qi * 16 + c16;
                bf16x8 pa = *(const bf16x8*)&PT[w][sw64(prow, kc * 32 + seg * 8)];
#pragma unroll
                for (int dt = 0; dt < 4; ++dt)
                    acc[qi][dt] = __builtin_amdgcn_mfma_f32_16x16x32_bf16(pa, vf[dt], acc[qi][dt], 0, 0, 0);
            }
        }

        __syncthreads();   // compiler drains vmcnt before barrier -> next tile staged & safe to overwrite
    }

    // ---- epilogue: D layout col=c16(+dt*16), row=seg*4+r(+qi*16)
    float* op = Og + ((size_t)b * SEQ + q0) * DM + h * HD;
#pragma unroll
    for (int qi = 0; qi < 2; ++qi)
#pragma unroll
        for (int dt = 0; dt < 4; ++dt)
#pragma unroll
            for (int r = 0; r < 4; ++r)
                op[(size_t)(qi * 16 + seg * 4 + r) * DM + dt * 16 + c16] = acc[qi][dt][r];
}

extern "C" void kernel_launch(void* const* d_in, const int* in_sizes, int n_in,
                              void* d_out, int out_size, void* d_ws, size_t ws_size,
                              hipStream_t stream) {
    const float* v = (const float*)d_in[0];
    const float* k = (const float*)d_in[1];
    const float* q = (const float*)d_in[2];
    float* out = (float*)d_out;
    __bf16* ws = (__bf16*)d_ws;
    (void)in_sizes; (void)n_in; (void)out_size; (void)ws_size;

    psa_prep<<<dim3(6144), dim3(256), 0, stream>>>(v, k, q, ws);
    psa_main<<<dim3(BH * (SEQ / QB)), dim3(256), 0, stream>>>(ws, out);
}